// Round 8
// baseline (314.302 us; speedup 1.0000x reference)
//
#include <hip/hip_runtime.h>

typedef __attribute__((ext_vector_type(8))) _Float16 f16x8;   // 8 fp16 = 4 VGPRs
typedef __attribute__((ext_vector_type(16))) float f32x16;    // 32x32 C/D
constexpr int kC  = 128;
constexpr int kCH = 64;
constexpr int kN  = 4096;
constexpr float kLog2e = 1.4426950408889634f;

__device__ __forceinline__ float h2f(unsigned short u) {
    union { _Float16 h; unsigned short u; } cv;
    cv.u = u;
    return (float)cv.h;
}
__device__ __forceinline__ unsigned pkrtz(float a, float b) {
    union { __fp16 __attribute__((ext_vector_type(2))) v; unsigned u; } cv;
    cv.v = __builtin_amdgcn_cvt_pkrtz(a, b);
    return cv.u;
}

// ---------------------------------------------------------------------------
// Unified pre-pass. blockIdx.y in [0,40): slice = y>>3 (y<32), b = y&7.
//   0: Q = relu(Wt.tgt+bt)*log2e -> fp16 [b][n][64]
//   1: K = relu(Wr.ref+br)      -> fp16 [b][n][64]
//   2/3: gate halves = Wo.tgt+bo -> fp32 [b][128][n]
//   y in [32,40): V convert ref fp32 -> fp16 (slice 4; b = y&7)
// ---------------------------------------------------------------------------
__global__ __launch_bounds__(256, 3) void proj_all(
    const float* __restrict__ tgt, const float* __restrict__ ref,
    const float* __restrict__ Wt, const float* __restrict__ Wr,
    const float* __restrict__ Wo, const float* __restrict__ bt,
    const float* __restrict__ br, const float* __restrict__ bo,
    unsigned short* __restrict__ Qw, unsigned short* __restrict__ Kw,
    unsigned short* __restrict__ Vw, float* __restrict__ Gw)
{
    __shared__ float ws[128 * 65];
    const int t = threadIdx.x;
    const int y = blockIdx.y;
    const int b = y & 7;

    if (y >= 32) {   // V convert: this (x,b) block does 8192 float4s of ref[b]
        const size_t base4 = ((size_t)b * kC * kN + (size_t)blockIdx.x * 32768) / 4;
        #pragma unroll
        for (int i = 0; i < 32; ++i) {
            size_t j = base4 + (size_t)i * 256 + t;
            float4 v = ((const float4*)ref)[j];
            ((uint2*)Vw)[j] = make_uint2(pkrtz(v.x, v.y), pkrtz(v.z, v.w));
        }
        return;
    }

    const int slice = y >> 3;
    const int tokb = blockIdx.x * 256;
    const float* X; const float* W; const float* bias;
    int oc0 = 0; float scale = 1.0f;
    if (slice == 0)      { X = tgt; W = Wt; bias = bt; scale = kLog2e; }
    else if (slice == 1) { X = ref; W = Wr; bias = br; }
    else                 { X = tgt; W = Wo; bias = bo; oc0 = (slice - 2) * 64; }

    #pragma unroll
    for (int k = 0; k < 32; ++k) {
        int i = t + k * 256;
        int c = i & 127, oc = i >> 7;
        ws[c * 65 + oc] = W[(size_t)(oc0 + oc) * kC + c] * scale;
    }
    __syncthreads();

    const int tokg = t >> 3, ocg = t & 7;
    const int tok0 = tokb + tokg * 8;
    float bv[8];
    #pragma unroll
    for (int j = 0; j < 8; ++j) bv[j] = bias[oc0 + ocg * 8 + j] * scale;
    float acc[8][8];
    #pragma unroll
    for (int i = 0; i < 8; ++i)
        #pragma unroll
        for (int j = 0; j < 8; ++j) acc[i][j] = bv[j];

    const float* Xb = X + ((size_t)b * kC) * kN + tok0;
    #pragma unroll 2
    for (int c = 0; c < kC; ++c) {
        float4 x0 = *(const float4*)(Xb + (size_t)c * kN);
        float4 x1 = *(const float4*)(Xb + (size_t)c * kN + 4);
        float4 w0 = *(const float4*)(ws + c * 65 + ocg * 8);
        float4 w1 = *(const float4*)(ws + c * 65 + ocg * 8 + 4);
        float xx[8] = {x0.x, x0.y, x0.z, x0.w, x1.x, x1.y, x1.z, x1.w};
        float ww[8] = {w0.x, w0.y, w0.z, w0.w, w1.x, w1.y, w1.z, w1.w};
        #pragma unroll
        for (int i = 0; i < 8; ++i)
            #pragma unroll
            for (int j = 0; j < 8; ++j) acc[i][j] = fmaf(xx[i], ww[j], acc[i][j]);
    }

    if (slice < 2) {
        unsigned short* out = slice ? Kw : Qw;
        #pragma unroll
        for (int i = 0; i < 8; ++i) {
            uint4 pk;
            pk.x = pkrtz(fmaxf(acc[i][0], 0.f), fmaxf(acc[i][1], 0.f));
            pk.y = pkrtz(fmaxf(acc[i][2], 0.f), fmaxf(acc[i][3], 0.f));
            pk.z = pkrtz(fmaxf(acc[i][4], 0.f), fmaxf(acc[i][5], 0.f));
            pk.w = pkrtz(fmaxf(acc[i][6], 0.f), fmaxf(acc[i][7], 0.f));
            *(uint4*)(out + ((size_t)b * kN + tok0 + i) * kCH + ocg * 8) = pk;
        }
    } else {
        #pragma unroll
        for (int j = 0; j < 8; ++j) {
            size_t base = ((size_t)b * kC + oc0 + ocg * 8 + j) * kN + tok0;
            *(float4*)(Gw + base)     = make_float4(acc[0][j], acc[1][j], acc[2][j], acc[3][j]);
            *(float4*)(Gw + base + 4) = make_float4(acc[4][j], acc[5][j], acc[6][j], acc[7][j]);
        }
    }
}

// ---------------------------------------------------------------------------
// Flash attention, fp16 MFMA 32x32x16, S^T = K.Q^T.
// Wave = 32 Q-rows (halves the LDS-port traffic per output vs 16x16 — that
// port is the measured bottleneck). Block = 2 waves = 64 rows; 512 blocks.
// C-layout (m74/m101): col=lane&31 (token for S^T / ch for O),
// row=(reg&3)+8*(reg>>2)+4*(lane>>5). One shfl_xor(32) per softmax reduce.
// LDS ping-pong (one barrier/tile), XOR chunk^(row&7) swizzle everywhere.
// ---------------------------------------------------------------------------
__global__ __launch_bounds__(128) void flash6_kernel(
    const unsigned short* __restrict__ Qw,   // [8][4096][64] fp16 (x log2e)
    const unsigned short* __restrict__ Kw,   // [8][4096][64] fp16
    const unsigned short* __restrict__ Vw,   // [8][128][4096] fp16
    const float* __restrict__ Gw,            // [8][128][4096] fp32 gate
    float* __restrict__ out)                 // [8][128][4096]
{
    __shared__ __align__(16) unsigned short Ks[2][64 * 64];
    __shared__ __align__(16) unsigned short Vs[2][128 * 64];
    __shared__ __align__(16) unsigned short Ps[64 * 64];

    const int t = threadIdx.x;               // 128 threads
    const int b = blockIdx.x & 7;
    const int n0 = (blockIdx.x >> 3) << 6;
    const int w = t >> 6, lane = t & 63;
    const int h = lane >> 5, lm = lane & 31;
    const int row_q = w * 32 + lm;           // this lane's token (S col)
    const int sw = lm & 7;

    const unsigned short* Qb = Qw + ((size_t)b * kN) * kCH;
    const unsigned short* Kb = Kw + ((size_t)b * kN) * kCH;
    const unsigned short* Vb = Vw + ((size_t)b * kC) * kN;

    // Q fragments in registers: B[n=lm][k=16i+8h+j]
    f16x8 qf[4];
    #pragma unroll
    for (int i = 0; i < 4; ++i)
        qf[i] = *(const f16x8*)(Qb + (size_t)(n0 + row_q) * kCH + 16 * i + 8 * h);

    // staging geometry (contiguous 2KB per instruction, swizzled LDS dest)
    const int srw = t >> 3;                  // 0..15
    const int sc  = t & 7;
    const int sgl = sc << 3;                 // global chunk (shorts)
    const int sls = ((sc ^ (srw & 7)) << 3); // swizzled chunk (shorts)

    // fragment-read chunk offsets: chunk (2i+h) ^ sw
    int fo[4];
    #pragma unroll
    for (int i = 0; i < 4; ++i) fo[i] = ((2 * i + h) ^ sw) << 3;
    // P b64 write offsets: key 32g2+8g+4h -> chunk (4g2+g)^sw, half h
    int pw[8];
    #pragma unroll
    for (int g2 = 0; g2 < 2; ++g2)
        #pragma unroll
        for (int g = 0; g < 4; ++g)
            pw[g2 * 4 + g] = row_q * 64 + (((4 * g2 + g) ^ sw) << 3) + 4 * h;

    f32x16 O[4];
    #pragma unroll
    for (int cb = 0; cb < 4; ++cb)
        #pragma unroll
        for (int r = 0; r < 16; ++r) O[cb][r] = 0.0f;
    float m_run = 0.0f, l_run = 0.0f;        // exp2 domain, S >= 0

    {   // prologue: stage tile 0 into buffer 0
        #pragma unroll
        for (int i = 0; i < 4; ++i) {
            int r = srw + 16 * i;
            *(uint4*)(Ks[0] + r * 64 + sls) = *(const uint4*)(Kb + (size_t)r * kCH + sgl);
        }
        #pragma unroll
        for (int i = 0; i < 8; ++i) {
            int r = srw + 16 * i;
            *(uint4*)(Vs[0] + r * 64 + sls) = *(const uint4*)(Vb + (size_t)r * kN + sgl);
        }
    }

    for (int kt = 0; kt < kN / 64; ++kt) {
        const int cur = kt & 1;
        __syncthreads();

        uint4 kr[4], vr[8];
        const bool pre = (kt < kN / 64 - 1);
        if (pre) {
            const int m0 = (kt + 1) << 6;
            #pragma unroll
            for (int i = 0; i < 4; ++i)
                kr[i] = *(const uint4*)(Kb + (size_t)(m0 + srw + 16 * i) * kCH + sgl);
            #pragma unroll
            for (int i = 0; i < 8; ++i)
                vr[i] = *(const uint4*)(Vb + (size_t)(srw + 16 * i) * kN + m0 + sgl);
        }

        // ---- QK^T -> S^T: two 32-key groups ----
        f32x16 s[2];
        #pragma unroll
        for (int g2 = 0; g2 < 2; ++g2) {
            const unsigned short* krow = Ks[cur] + (g2 * 32 + lm) * 64;
            f32x16 acc;
            #pragma unroll
            for (int r = 0; r < 16; ++r) acc[r] = 0.0f;
            #pragma unroll
            for (int i = 0; i < 4; ++i) {
                f16x8 kf = *(const f16x8*)(krow + fo[i]);
                acc = __builtin_amdgcn_mfma_f32_32x32x16_f16(kf, qf[i], acc, 0, 0, 0);
            }
            s[g2] = acc;
        }

        // ---- online softmax over 64 keys (token = lm; halves via xor 32) ----
        float mloc = 0.0f;
        #pragma unroll
        for (int g2 = 0; g2 < 2; ++g2)
            #pragma unroll
            for (int r = 0; r < 16; ++r) mloc = fmaxf(mloc, s[g2][r]);
        mloc = fmaxf(mloc, __shfl_xor(mloc, 32, 64));
        const bool upd = __any(mloc > m_run);
        const float mnew = upd ? fmaxf(m_run, mloc) : m_run;

        float psum = 0.0f;
        #pragma unroll
        for (int g2 = 0; g2 < 2; ++g2) {
            #pragma unroll
            for (int g = 0; g < 4; ++g) {
                unsigned plo = pkrtz(__builtin_amdgcn_exp2f(s[g2][4 * g + 0] - mnew),
                                     __builtin_amdgcn_exp2f(s[g2][4 * g + 1] - mnew));
                unsigned phi = pkrtz(__builtin_amdgcn_exp2f(s[g2][4 * g + 2] - mnew),
                                     __builtin_amdgcn_exp2f(s[g2][4 * g + 3] - mnew));
                psum += (h2f(plo & 0xffff) + h2f(plo >> 16)) +
                        (h2f(phi & 0xffff) + h2f(phi >> 16));
                *(uint2*)(Ps + pw[g2 * 4 + g]) = make_uint2(plo, phi);
            }
        }
        psum += __shfl_xor(psum, 32, 64);

        if (upd) {
            float alpha = __builtin_amdgcn_exp2f(m_run - mnew);
            #pragma unroll
            for (int g = 0; g < 4; ++g) {
                float a0 = __shfl(alpha, 4 * h + 8 * g + 0, 64);
                float a1 = __shfl(alpha, 4 * h + 8 * g + 1, 64);
                float a2 = __shfl(alpha, 4 * h + 8 * g + 2, 64);
                float a3 = __shfl(alpha, 4 * h + 8 * g + 3, 64);
                #pragma unroll
                for (int cb = 0; cb < 4; ++cb) {
                    O[cb][4 * g + 0] *= a0; O[cb][4 * g + 1] *= a1;
                    O[cb][4 * g + 2] *= a2; O[cb][4 * g + 3] *= a3;
                }
            }
            l_run = l_run * alpha + psum;
            m_run = mnew;
        } else {
            l_run += psum;
        }

        // ---- PV: A=P[token][key], B=V[ch][key] ----
        f16x8 pf[4];
        #pragma unroll
        for (int i = 0; i < 4; ++i)
            pf[i] = *(const f16x8*)(Ps + row_q * 64 + fo[i]);
        #pragma unroll
        for (int cb = 0; cb < 4; ++cb) {
            const unsigned short* vrow = Vs[cur] + (cb * 32 + lm) * 64;
            f32x16 acc = O[cb];
            #pragma unroll
            for (int i = 0; i < 4; ++i) {
                f16x8 vf = *(const f16x8*)(vrow + fo[i]);
                acc = __builtin_amdgcn_mfma_f32_32x32x16_f16(pf[i], vf, acc, 0, 0, 0);
            }
            O[cb] = acc;
        }

        if (pre) {
            unsigned short* Kn = Ks[cur ^ 1];
            unsigned short* Vn = Vs[cur ^ 1];
            #pragma unroll
            for (int i = 0; i < 4; ++i)
                *(uint4*)(Kn + (srw + 16 * i) * 64 + sls) = kr[i];
            #pragma unroll
            for (int i = 0; i < 8; ++i)
                *(uint4*)(Vn + (srw + 16 * i) * 64 + sls) = vr[i];
        }
    }

    // ---- epilogue: normalize (inv per token via shfl), gate, store float4 ----
    float inv = 1.0f / l_run;                // l for token lm (both halves agree)
    const float* Gb = Gw + ((size_t)b * kC) * kN;
    float* Ob = out + ((size_t)b * kC) * kN;
    #pragma unroll
    for (int g = 0; g < 4; ++g) {
        float i0 = __shfl(inv, 4 * h + 8 * g + 0, 64);
        float i1 = __shfl(inv, 4 * h + 8 * g + 1, 64);
        float i2 = __shfl(inv, 4 * h + 8 * g + 2, 64);
        float i3 = __shfl(inv, 4 * h + 8 * g + 3, 64);
        #pragma unroll
        for (int cb = 0; cb < 4; ++cb) {
            int c = cb * 32 + lm;
            size_t base = (size_t)c * kN + n0 + w * 32 + 4 * h + 8 * g;
            float4 gt = *(const float4*)(Gb + base);
            float4 res;
            res.x = O[cb][4 * g + 0] * i0 * gt.x;
            res.y = O[cb][4 * g + 1] * i1 * gt.y;
            res.z = O[cb][4 * g + 2] * i2 * gt.z;
            res.w = O[cb][4 * g + 3] * i3 * gt.w;
            *(float4*)(Ob + base) = res;
        }
    }
}

// ---------------------------------------------------------------------------
extern "C" void kernel_launch(void* const* d_in, const int* in_sizes, int n_in,
                              void* d_out, int out_size, void* d_ws, size_t ws_size,
                              hipStream_t stream) {
    const float* tgt   = (const float*)d_in[0];
    const float* ref   = (const float*)d_in[1];
    const float* W_tgt = (const float*)d_in[2];
    const float* b_tgt = (const float*)d_in[3];
    const float* W_ref = (const float*)d_in[4];
    const float* b_ref = (const float*)d_in[5];
    const float* W_out = (const float*)d_in[6];
    const float* b_out = (const float*)d_in[7];
    float* out = (float*)d_out;

    const size_t QK = (size_t)8 * kN * kCH;              // fp16 -> 4 MB each
    const size_t CV = (size_t)8 * kC * kN;               // fp16 -> 8 MB
    unsigned short* Qw = (unsigned short*)d_ws;          // 4 MB
    unsigned short* Kw = Qw + QK;                        // 4 MB
    unsigned short* Vw = Kw + QK;                        // 8 MB
    float*          Gw = (float*)(Vw + CV);              // 16 MB (total 32 MB)

    proj_all<<<dim3(16, 40), 256, 0, stream>>>(tgt, ref, W_tgt, W_ref, W_out,
                                               b_tgt, b_ref, b_out, Qw, Kw, Vw, Gw);
    flash6_kernel<<<dim3(512), 128, 0, stream>>>(Qw, Kw, Vw, Gw, out);
}